// Round 2
// baseline (909.199 us; speedup 1.0000x reference)
//
#include <hip/hip_runtime.h>
#include <math.h>
#include <stdint.h>

#define EPS 1e-5f

typedef __bf16 bf16x8 __attribute__((ext_vector_type(8)));
typedef __bf16 bf16x4 __attribute__((ext_vector_type(4)));
typedef float  f32x4  __attribute__((ext_vector_type(4)));

constexpr int D  = 1024;   // hidden dim (fixed by the reference)

// ---------------------------------------------------------------------------
// Pre-pass: per row compute sum(v*v), projection scale s, write bf16(s*v)
// and q = s^2 * sumsq (projected squared norm). One 256-thread block per row.
// ---------------------------------------------------------------------------
__global__ __launch_bounds__(256) void project_convert_kernel(
    const float* __restrict__ src, __bf16* __restrict__ dst,
    float* __restrict__ q_out)
{
    const int row = blockIdx.x;
    const int t = threadIdx.x;
    const float4 v = *(const float4*)(src + (size_t)row * D + t * 4);
    float s = v.x * v.x + v.y * v.y + v.z * v.z + v.w * v.w;
#pragma unroll
    for (int off = 32; off > 0; off >>= 1) s += __shfl_down(s, off);
    __shared__ float partial[4];
    __shared__ float s_scale;
    if ((t & 63) == 0) partial[t >> 6] = s;
    __syncthreads();
    if (t == 0) {
        float tot = partial[0] + partial[1] + partial[2] + partial[3];
        float norm = sqrtf(tot);
        float sc = fminf((1.0f - EPS) / (norm + 1e-10f), 1.0f);
        s_scale = sc;
        q_out[row] = sc * sc * tot;   // projected ||.||^2, fp32-exact path
    }
    __syncthreads();
    const float sc = s_scale;
    bf16x4 o = { (__bf16)(v.x * sc), (__bf16)(v.y * sc),
                 (__bf16)(v.z * sc), (__bf16)(v.w * sc) };
    *(bf16x4*)(dst + (size_t)row * D + t * 4) = o;
}

// async global->LDS, 16 B per lane. LDS dest must be wave-uniform base + lane*16.
__device__ __forceinline__ void gload16(const void* g, void* l)
{
    __builtin_amdgcn_global_load_lds(
        (const __attribute__((address_space(1))) uint32_t*)g,
        (__attribute__((address_space(3))) uint32_t*)l, 16, 0, 0);
}

#define WAITVM(N) asm volatile("s_waitcnt vmcnt(" #N ")" ::: "memory")
#define WAITLGKM0 asm volatile("s_waitcnt lgkmcnt(0)" ::: "memory")

// ---------------------------------------------------------------------------
// 256x256 bf16 GEMM, 8 waves (2M x 4N, 128x64 per wave), BK=64, double-buffered
// LDS (128 KB) with COUNTED vmcnt pipelining: the next K-tile's 8 global_load_lds
// stay in flight across the barrier (never drain to 0 in the main loop).
// LDS layout: linear [256][64] bf16 rows (128 B), 16B-granule XOR swizzle
// g_phys = g_log ^ (row&7) realized by permuting the per-lane GLOBAL source
// (rule 21: linear dest + inverse-swz source + swz on read).
// Fused hyperbolic-distance epilogue.
// ---------------------------------------------------------------------------
__global__ __launch_bounds__(512, 2) void hyp_gemm_256_kernel(
    const __bf16* __restrict__ Xb, const __bf16* __restrict__ Yb,
    const float* __restrict__ xq, const float* __restrict__ yq,
    float* __restrict__ out, int V, int nbx)
{
    constexpr int BK = 64;          // bf16 per K-tile (128 B rows)
    constexpr int KT = D / BK;      // 16 K-tiles
    constexpr int BUFB = 256 * BK * 2;  // 32768 B per operand per buffer

    __shared__ __bf16 As[2 * 256 * BK];   // 64 KB (2 buffers)
    __shared__ __bf16 Bs[2 * 256 * BK];   // 64 KB

    // XCD-chunked bijective swizzle (gridDim.x = 2000, %8==0)
    const int wg = blockIdx.x;
    const int c = (gridDim.x & 7) ? wg : ((wg & 7) * (gridDim.x >> 3) + (wg >> 3));
    const int m0 = (c / nbx) * 256;
    const int n0 = (c % nbx) * 256;

    const int t = threadIdx.x;      // 0..511

    // ---- staging map: one G::load = 512 lanes x 16 B = 64 rows x 128 B.
    // thread t covers row (t>>3) + 64j (j=0..3), 16B granule t&7 (pre-swizzled src)
    const int rt = t >> 3;                    // 0..63
    const int gsrc = (t & 7) ^ (rt & 7);      // inverse-swizzled source granule
    const char* xg = (const char*)(Xb + (size_t)(m0 + rt) * D) + gsrc * 16;
    const char* yg = (const char*)(Yb + (size_t)(n0 + rt) * D) + gsrc * 16;

    // ---- wave/fragment map: 8 waves = 2M x 4N, each 128x64 via 8x4 16x16 frags
    const int lane = t & 63;
    const int ln   = lane & 15;
    const int quad = lane >> 4;
    const int wave = t >> 6;
    const int wm = (wave >> 2) * 128;
    const int wn = (wave & 3) * 64;
    const int swz = ln & 7;                   // == row&7 of every fragment row

    f32x4 acc[8][4] = {};

    auto STAGE = [&](int kt, int b) {
        const int ko = kt * 128;              // byte offset along a row
#pragma unroll
        for (int j = 0; j < 4; ++j)
            gload16(xg + j * 131072 + ko, (char*)As + b * BUFB + j * 8192 + t * 16);
#pragma unroll
        for (int j = 0; j < 4; ++j)
            gload16(yg + j * 131072 + ko, (char*)Bs + b * BUFB + j * 8192 + t * 16);
    };

    auto COMPUTE = [&](int b) {
        const char* Ab = (const char*)As + b * BUFB;
        const char* Bb = (const char*)Bs + b * BUFB;
#pragma unroll
        for (int ks = 0; ks < 2; ++ks) {
            const int ga = ((ks * 4 + quad) ^ swz) * 16;
            bf16x8 af[8], bfr[4];
#pragma unroll
            for (int i = 0; i < 8; ++i)
                af[i] = *(const bf16x8*)(Ab + (wm + i * 16 + ln) * 128 + ga);
#pragma unroll
            for (int i = 0; i < 4; ++i)
                bfr[i] = *(const bf16x8*)(Bb + (wn + i * 16 + ln) * 128 + ga);
            __builtin_amdgcn_s_setprio(1);
#pragma unroll
            for (int mt = 0; mt < 8; ++mt)
#pragma unroll
                for (int nt = 0; nt < 4; ++nt)
                    acc[mt][nt] = __builtin_amdgcn_mfma_f32_16x16x32_bf16(
                        af[mt], bfr[nt], acc[mt][nt], 0, 0, 0);
            __builtin_amdgcn_s_setprio(0);
        }
    };

    STAGE(0, 0);
#pragma unroll 2
    for (int kt = 0; kt < KT; ++kt) {
        const int b = kt & 1;
        if (kt + 1 < KT) {
            STAGE(kt + 1, b ^ 1);             // issue next tile: stays in flight
            WAITVM(8);                        // only tile kt's 8 loads must land
        } else {
            WAITVM(0);
        }
        __builtin_amdgcn_sched_barrier(0);
        __builtin_amdgcn_s_barrier();         // tile kt resident for all waves
        __builtin_amdgcn_sched_barrier(0);
        COMPUTE(b);
        WAITLGKM0;                            // all ds_reads of buf b retired
        __builtin_amdgcn_sched_barrier(0);
        __builtin_amdgcn_s_barrier();         // buf b safe to overwrite next iter
        __builtin_amdgcn_sched_barrier(0);
    }

    // ---------------- epilogue: hyperbolic distance ----------------
    // C/D layout: col = lane&15, row = quad*4 + reg  [m89-verified]
    float yqv[4], omy[4];
    int gcv[4];
#pragma unroll
    for (int nt = 0; nt < 4; ++nt) {
        const int gc = n0 + wn + nt * 16 + ln;
        gcv[nt] = gc;
        yqv[nt] = yq[gc];
        omy[nt] = 1.0f - yqv[nt];
    }
#pragma unroll
    for (int mt = 0; mt < 8; ++mt) {
#pragma unroll
        for (int r = 0; r < 4; ++r) {
            const int gm = m0 + wm + mt * 16 + quad * 4 + r;
            const float xqv = xq[gm];
            const float omx = 1.0f - xqv;
            float* orow = out + (size_t)gm * V;
#pragma unroll
            for (int nt = 0; nt < 4; ++nt) {
                const float dot = acc[mt][nt][r];   // already projected dot
                float d2 = fmaxf(xqv + yqv[nt] - 2.0f * dot, 0.0f);
                float d  = __builtin_amdgcn_sqrtf(d2);
                float denom = omx * omy[nt] + EPS;
                float w = d * __builtin_amdgcn_rcpf(denom);   // = t/2, t = 2d/denom
                float res;
                if (__builtin_expect(w >= 4.0f, 1)) {
                    // arccosh(1+t) ~= log(2+2t), err < 4e-3 for t >= 8
                    res = __logf(2.0f + 4.0f * w);
                } else {
                    float arg = fmaxf(1.0f + 2.0f * w, 1.0f + EPS);
                    res = __logf(arg + __builtin_amdgcn_sqrtf(arg * arg - 1.0f));
                }
                orow[gcv[nt]] = -res;
            }
        }
    }
}

// ---------------------------------------------------------------------------
// FALLBACK PATH (fp32 inputs, 288 KB workspace; verified in round 0)
// ---------------------------------------------------------------------------
constexpr int FBM = 128, FBN = 128;
constexpr int LDT = 40;  // 32 + 8 padded LDS row stride (bf16)

__global__ __launch_bounds__(256) void row_stats_kernel(
    const float* __restrict__ src, float* __restrict__ scale_out,
    float* __restrict__ sq_out)
{
    const int row = blockIdx.x;
    const int t = threadIdx.x;
    const float4 v = *(const float4*)(src + (size_t)row * D + t * 4);
    float s = v.x * v.x + v.y * v.y + v.z * v.z + v.w * v.w;
#pragma unroll
    for (int off = 32; off > 0; off >>= 1) s += __shfl_down(s, off);
    __shared__ float partial[4];
    if ((t & 63) == 0) partial[t >> 6] = s;
    __syncthreads();
    if (t == 0) {
        float tot = partial[0] + partial[1] + partial[2] + partial[3];
        float norm = sqrtf(tot);
        float sc = fminf((1.0f - EPS) / (norm + 1e-10f), 1.0f);
        scale_out[row] = sc;
        sq_out[row] = sc * sc * tot;
    }
}

__global__ __launch_bounds__(256) void hyp_gemm_kernel(
    const float* __restrict__ X, const float* __restrict__ Y,
    const float* __restrict__ sx, const float* __restrict__ xq,
    const float* __restrict__ sy, const float* __restrict__ yq,
    float* __restrict__ out, int V)
{
    constexpr int BK = 32;
    __shared__ __bf16 As[FBM * LDT];
    __shared__ __bf16 Bs[FBN * LDT];

    const int t  = threadIdx.x;
    const int m0 = blockIdx.y * FBM;
    const int n0 = blockIdx.x * FBN;

    const int sr = t >> 3;
    const int scol = t & 7;

    const float* xg = X + (size_t)(m0 + sr) * D + scol * 4;
    const float* yg = Y + (size_t)(n0 + sr) * D + scol * 4;

    const int lane = t & 63;
    const int wave = t >> 6;
    const int wm = (wave & 1) * 64;
    const int wn = (wave >> 1) * 64;
    const int ln = lane & 15;
    const int quad = lane >> 4;

    f32x4 acc[4][4] = {};

    float4 pa[4], pb[4];
#pragma unroll
    for (int j = 0; j < 4; ++j) {
        pa[j] = *(const float4*)(xg + (size_t)j * 32 * D);
        pb[j] = *(const float4*)(yg + (size_t)j * 32 * D);
    }

    constexpr int KT = D / BK;
    for (int kt = 0; kt < KT; ++kt) {
        __syncthreads();
#pragma unroll
        for (int j = 0; j < 4; ++j) {
            bf16x4 a4 = { (__bf16)pa[j].x, (__bf16)pa[j].y, (__bf16)pa[j].z, (__bf16)pa[j].w };
            bf16x4 b4 = { (__bf16)pb[j].x, (__bf16)pb[j].y, (__bf16)pb[j].z, (__bf16)pb[j].w };
            *(bf16x4*)&As[(sr + 32 * j) * LDT + scol * 4] = a4;
            *(bf16x4*)&Bs[(sr + 32 * j) * LDT + scol * 4] = b4;
        }
        __syncthreads();
        if (kt + 1 < KT) {
            const int koff = (kt + 1) * BK;
#pragma unroll
            for (int j = 0; j < 4; ++j) {
                pa[j] = *(const float4*)(xg + (size_t)j * 32 * D + koff);
                pb[j] = *(const float4*)(yg + (size_t)j * 32 * D + koff);
            }
        }
        bf16x8 af[4], bfr[4];
#pragma unroll
        for (int i = 0; i < 4; ++i) {
            af[i]  = *(const bf16x8*)&As[(wm + i * 16 + ln) * LDT + quad * 8];
            bfr[i] = *(const bf16x8*)&Bs[(wn + i * 16 + ln) * LDT + quad * 8];
        }
#pragma unroll
        for (int mt = 0; mt < 4; ++mt)
#pragma unroll
            for (int nt = 0; nt < 4; ++nt)
                acc[mt][nt] = __builtin_amdgcn_mfma_f32_16x16x32_bf16(
                    af[mt], bfr[nt], acc[mt][nt], 0, 0, 0);
    }

    float yqv[4], syv[4];
    int gcv[4];
#pragma unroll
    for (int nt = 0; nt < 4; ++nt) {
        const int gc = n0 + wn + nt * 16 + ln;
        gcv[nt] = gc;
        yqv[nt] = yq[gc];
        syv[nt] = sy[gc];
    }
#pragma unroll
    for (int mt = 0; mt < 4; ++mt) {
#pragma unroll
        for (int r = 0; r < 4; ++r) {
            const int gm = m0 + wm + mt * 16 + quad * 4 + r;
            const float xqv = xq[gm];
            const float sxv = sx[gm];
            const float omx = 1.0f - xqv;
            float* orow = out + (size_t)gm * V;
#pragma unroll
            for (int nt = 0; nt < 4; ++nt) {
                const float raw = acc[mt][nt][r];
                const float dot = sxv * syv[nt] * raw;
                float d2 = xqv + yqv[nt] - 2.0f * dot;
                float dd = __builtin_amdgcn_sqrtf(fmaxf(d2, 0.0f));
                float denom = omx * (1.0f - yqv[nt]) + EPS;
                float arg = 1.0f + 2.0f * dd * __builtin_amdgcn_rcpf(denom);
                arg = fmaxf(arg, 1.0f + EPS);
                float res = -__logf(arg + __builtin_amdgcn_sqrtf(arg * arg - 1.0f));
                orow[gcv[nt]] = res;
            }
        }
    }
}

// ---------------------------------------------------------------------------
extern "C" void kernel_launch(void* const* d_in, const int* in_sizes, int n_in,
                              void* d_out, int out_size, void* d_ws, size_t ws_size,
                              hipStream_t stream)
{
    const float* X = (const float*)d_in[0];   // hidden_states (N x D) fp32
    const float* Y = (const float*)d_in[1];   // weight        (V x D) fp32
    float* out = (float*)d_out;               // logits (N x V) fp32

    const int N = in_sizes[0] / D;   // 4096
    const int V = in_sizes[1] / D;   // 32000

    // fast path workspace: bf16 X (N*D) + bf16 Y (V*D) + xq (N) + yq (V)
    const size_t need = (size_t)(N + V) * D * 2 + (size_t)(N + V) * 4;

    if (ws_size >= need && (N % 256) == 0 && (V % 256) == 0) {
        __bf16* Xb = (__bf16*)d_ws;
        __bf16* Yb = Xb + (size_t)N * D;
        float* xq = (float*)(Yb + (size_t)V * D);
        float* yq = xq + N;

        project_convert_kernel<<<N, 256, 0, stream>>>(X, Xb, xq);
        project_convert_kernel<<<V, 256, 0, stream>>>(Y, Yb, yq);

        const int nbx = V / 256;               // 125
        const int nwg = nbx * (N / 256);       // 2000
        hyp_gemm_256_kernel<<<nwg, 512, 0, stream>>>(Xb, Yb, xq, yq, out, V, nbx);
    } else {
        float* sx = (float*)d_ws;
        float* xq = sx + N;
        float* sy = xq + N;
        float* yq = sy + V;

        row_stats_kernel<<<N, 256, 0, stream>>>(X, sx, xq);
        row_stats_kernel<<<V, 256, 0, stream>>>(Y, sy, yq);

        dim3 grid(V / FBN, N / FBM);
        hyp_gemm_kernel<<<grid, 256, 0, stream>>>(X, Y, sx, xq, sy, yq, out, V);
    }
}

// Round 3
// 899.441 us; speedup vs baseline: 1.0108x; 1.0108x over previous
//
#include <hip/hip_runtime.h>
#include <math.h>
#include <stdint.h>

#define EPS 1e-5f

typedef __bf16 bf16x8 __attribute__((ext_vector_type(8)));
typedef __bf16 bf16x4 __attribute__((ext_vector_type(4)));
typedef float  f32x4  __attribute__((ext_vector_type(4)));

constexpr int D  = 1024;   // hidden dim (fixed by the reference)

// ---------------------------------------------------------------------------
// Pre-pass: per row compute sum(v*v), projection scale s, write bf16(s*v)
// and q = s^2 * sumsq (projected squared norm). One 256-thread block per row.
// ---------------------------------------------------------------------------
__global__ __launch_bounds__(256) void project_convert_kernel(
    const float* __restrict__ src, __bf16* __restrict__ dst,
    float* __restrict__ q_out)
{
    const int row = blockIdx.x;
    const int t = threadIdx.x;
    const float4 v = *(const float4*)(src + (size_t)row * D + t * 4);
    float s = v.x * v.x + v.y * v.y + v.z * v.z + v.w * v.w;
#pragma unroll
    for (int off = 32; off > 0; off >>= 1) s += __shfl_down(s, off);
    __shared__ float partial[4];
    __shared__ float s_scale;
    if ((t & 63) == 0) partial[t >> 6] = s;
    __syncthreads();
    if (t == 0) {
        float tot = partial[0] + partial[1] + partial[2] + partial[3];
        float norm = sqrtf(tot);
        float sc = fminf((1.0f - EPS) / (norm + 1e-10f), 1.0f);
        s_scale = sc;
        q_out[row] = sc * sc * tot;   // projected ||.||^2, fp32-exact path
    }
    __syncthreads();
    const float sc = s_scale;
    bf16x4 o = { (__bf16)(v.x * sc), (__bf16)(v.y * sc),
                 (__bf16)(v.z * sc), (__bf16)(v.w * sc) };
    *(bf16x4*)(dst + (size_t)row * D + t * 4) = o;
}

// async global->LDS, 16 B per lane. LDS dest must be wave-uniform base + lane*16.
__device__ __forceinline__ void gload16(const void* g, void* l)
{
    __builtin_amdgcn_global_load_lds(
        (const __attribute__((address_space(1))) uint32_t*)g,
        (__attribute__((address_space(3))) uint32_t*)l, 16, 0, 0);
}

#define WAITVM(N) asm volatile("s_waitcnt vmcnt(" #N ")" ::: "memory")

// ---------------------------------------------------------------------------
// 256x256 bf16 GEMM, 8 waves (2M x 4N, 128x64 per wave), BK=32, FOUR LDS
// buffers (4 x 16 KB per operand = 128 KB total), staging runs TWO K-tiles
// ahead so the per-tile boundary wait is vmcnt(8) against loads issued two
// full compute-tiles earlier.  ONE barrier per K-tile (overwrite target was
// last read 4 tiles ago; wave drift bounded by the single rendezvous).
// LDS rows are 64 B (4 x 16B granules); swizzle  g_phys = g_log ^ ((row>>1)&3)
// realized by permuting the per-lane GLOBAL source (linear LDS dest, rule 21).
// With this key the 16 row-lanes of a ds_read_b128 hit 8 distinct 16B slots
// -> uniform 2-way bank aliasing = free (m136).
// Fused hyperbolic-distance epilogue.
// ---------------------------------------------------------------------------
__global__ __launch_bounds__(512, 2) void hyp_gemm_256_kernel(
    const __bf16* __restrict__ Xb, const __bf16* __restrict__ Yb,
    const float* __restrict__ xq, const float* __restrict__ yq,
    float* __restrict__ out, int V, int nbx)
{
    constexpr int BK   = 32;            // bf16 per K-tile (64 B rows)
    constexpr int KT   = D / BK;        // 32 K-tiles
    constexpr int BUFB = 256 * BK * 2;  // 16384 B per operand per buffer

    __shared__ __bf16 As[4 * 256 * BK];   // 64 KB (4 buffers)
    __shared__ __bf16 Bs[4 * 256 * BK];   // 64 KB

    // XCD-chunked bijective swizzle (gridDim.x = 2000, %8==0)
    const int wg = blockIdx.x;
    const int c = (gridDim.x & 7) ? wg : ((wg & 7) * (gridDim.x >> 3) + (wg >> 3));
    const int m0 = (c / nbx) * 256;
    const int n0 = (c % nbx) * 256;

    const int t = threadIdx.x;      // 0..511

    // ---- staging map: one gload16 = 512 lanes x 16 B = 128 rows x 64 B.
    // thread t covers row (t>>2) + 128j (j=0..1), granule (t&3), source
    // granule pre-swizzled by key (row>>1)&3 = (t>>3)&3.
    const int rt   = t >> 2;                  // 0..127
    const int gsrc = (t & 3) ^ ((t >> 3) & 3);
    const char* xg = (const char*)(Xb + (size_t)(m0 + rt) * D) + gsrc * 16;
    const char* yg = (const char*)(Yb + (size_t)(n0 + rt) * D) + gsrc * 16;

    // ---- wave/fragment map: 8 waves = 2M x 4N, each 128x64 via 8x4 16x16 frags
    const int lane = t & 63;
    const int ln   = lane & 15;
    const int quad = lane >> 4;
    const int wave = t >> 6;
    const int wm = (wave >> 2) * 128;
    const int wn = (wave & 3) * 64;
    // fragment read: logical k-granule = quad, phys = quad ^ ((row>>1)&3),
    // and (row>>1)&3 == (ln>>1)&3 for all fragment rows (wm, i*16 are %4==0
    // after >>1).
    const int ga = (quad ^ ((ln >> 1) & 3)) * 16;

    f32x4 acc[8][4] = {};

    auto STAGE = [&](int kt, int b) {
        const int ko = kt * 64;               // byte offset along a row
        gload16(xg + ko,          (char*)As + b * BUFB + t * 16);
        gload16(xg + ko + 262144, (char*)As + b * BUFB + 8192 + t * 16);
        gload16(yg + ko,          (char*)Bs + b * BUFB + t * 16);
        gload16(yg + ko + 262144, (char*)Bs + b * BUFB + 8192 + t * 16);
    };

    auto COMPUTE = [&](int b) {
        const char* Ab = (const char*)As + b * BUFB;
        const char* Bb = (const char*)Bs + b * BUFB;
        bf16x8 af[8], bfr[4];
#pragma unroll
        for (int i = 0; i < 8; ++i)
            af[i] = *(const bf16x8*)(Ab + (wm + i * 16 + ln) * 64 + ga);
#pragma unroll
        for (int i = 0; i < 4; ++i)
            bfr[i] = *(const bf16x8*)(Bb + (wn + i * 16 + ln) * 64 + ga);
        __builtin_amdgcn_s_setprio(1);
#pragma unroll
        for (int mt = 0; mt < 8; ++mt)
#pragma unroll
            for (int nt = 0; nt < 4; ++nt)
                acc[mt][nt] = __builtin_amdgcn_mfma_f32_16x16x32_bf16(
                    af[mt], bfr[nt], acc[mt][nt], 0, 0, 0);
        __builtin_amdgcn_s_setprio(0);
    };

    // prologue: two tiles in flight before the first compute
    STAGE(0, 0);
    STAGE(1, 1);

#pragma unroll
    for (int kt = 0; kt < KT - 2; ++kt) {
        STAGE(kt + 2, (kt + 2) & 3);          // issue-only; lands whenever
        __builtin_amdgcn_sched_barrier(0);    // all prior vmem issued
        WAITVM(8);                            // tile kt's 4 loads landed
        __builtin_amdgcn_s_barrier();         // -> tile kt resident block-wide
        __builtin_amdgcn_sched_barrier(0);    // ds_reads stay below barrier
        COMPUTE(kt & 3);
    }
    // tail: kt = KT-2 (outstanding = last tile's 4), kt = KT-1
    __builtin_amdgcn_sched_barrier(0);
    WAITVM(4);
    __builtin_amdgcn_s_barrier();
    __builtin_amdgcn_sched_barrier(0);
    COMPUTE((KT - 2) & 3);
    __builtin_amdgcn_sched_barrier(0);
    WAITVM(0);
    __builtin_amdgcn_s_barrier();
    __builtin_amdgcn_sched_barrier(0);
    COMPUTE((KT - 1) & 3);

    // ---------------- epilogue: hyperbolic distance ----------------
    // C/D layout: col = lane&15, row = quad*4 + reg  [m89-verified]
    float yqv[4], omy[4];
    int gcv[4];
#pragma unroll
    for (int nt = 0; nt < 4; ++nt) {
        const int gc = n0 + wn + nt * 16 + ln;
        gcv[nt] = gc;
        yqv[nt] = yq[gc];
        omy[nt] = 1.0f - yqv[nt];
    }
#pragma unroll
    for (int mt = 0; mt < 8; ++mt) {
#pragma unroll
        for (int r = 0; r < 4; ++r) {
            const int gm = m0 + wm + mt * 16 + quad * 4 + r;
            const float xqv = xq[gm];
            const float omx = 1.0f - xqv;
            float* orow = out + (size_t)gm * V;
#pragma unroll
            for (int nt = 0; nt < 4; ++nt) {
                const float dot = acc[mt][nt][r];   // already projected dot
                float d2 = fmaxf(xqv + yqv[nt] - 2.0f * dot, 0.0f);
                float d  = __builtin_amdgcn_sqrtf(d2);
                float denom = omx * omy[nt] + EPS;
                float w = d * __builtin_amdgcn_rcpf(denom);   // = t/2, t = 2d/denom
                float res;
                if (__builtin_expect(w >= 4.0f, 1)) {
                    // arccosh(1+t) ~= log(2+2t), err < 4e-3 for t >= 8
                    res = __logf(2.0f + 4.0f * w);
                } else {
                    float arg = fmaxf(1.0f + 2.0f * w, 1.0f + EPS);
                    res = __logf(arg + __builtin_amdgcn_sqrtf(arg * arg - 1.0f));
                }
                orow[gcv[nt]] = -res;
            }
        }
    }
}

// ---------------------------------------------------------------------------
// FALLBACK PATH (fp32 inputs, 288 KB workspace; verified in round 0)
// ---------------------------------------------------------------------------
constexpr int FBM = 128, FBN = 128;
constexpr int LDT = 40;  // 32 + 8 padded LDS row stride (bf16)

__global__ __launch_bounds__(256) void row_stats_kernel(
    const float* __restrict__ src, float* __restrict__ scale_out,
    float* __restrict__ sq_out)
{
    const int row = blockIdx.x;
    const int t = threadIdx.x;
    const float4 v = *(const float4*)(src + (size_t)row * D + t * 4);
    float s = v.x * v.x + v.y * v.y + v.z * v.z + v.w * v.w;
#pragma unroll
    for (int off = 32; off > 0; off >>= 1) s += __shfl_down(s, off);
    __shared__ float partial[4];
    if ((t & 63) == 0) partial[t >> 6] = s;
    __syncthreads();
    if (t == 0) {
        float tot = partial[0] + partial[1] + partial[2] + partial[3];
        float norm = sqrtf(tot);
        float sc = fminf((1.0f - EPS) / (norm + 1e-10f), 1.0f);
        scale_out[row] = sc;
        sq_out[row] = sc * sc * tot;
    }
}

__global__ __launch_bounds__(256) void hyp_gemm_kernel(
    const float* __restrict__ X, const float* __restrict__ Y,
    const float* __restrict__ sx, const float* __restrict__ xq,
    const float* __restrict__ sy, const float* __restrict__ yq,
    float* __restrict__ out, int V)
{
    constexpr int BK = 32;
    __shared__ __bf16 As[FBM * LDT];
    __shared__ __bf16 Bs[FBN * LDT];

    const int t  = threadIdx.x;
    const int m0 = blockIdx.y * FBM;
    const int n0 = blockIdx.x * FBN;

    const int sr = t >> 3;
    const int scol = t & 7;

    const float* xg = X + (size_t)(m0 + sr) * D + scol * 4;
    const float* yg = Y + (size_t)(n0 + sr) * D + scol * 4;

    const int lane = t & 63;
    const int wave = t >> 6;
    const int wm = (wave & 1) * 64;
    const int wn = (wave >> 1) * 64;
    const int ln = lane & 15;
    const int quad = lane >> 4;

    f32x4 acc[4][4] = {};

    float4 pa[4], pb[4];
#pragma unroll
    for (int j = 0; j < 4; ++j) {
        pa[j] = *(const float4*)(xg + (size_t)j * 32 * D);
        pb[j] = *(const float4*)(yg + (size_t)j * 32 * D);
    }

    constexpr int KT = D / BK;
    for (int kt = 0; kt < KT; ++kt) {
        __syncthreads();
#pragma unroll
        for (int j = 0; j < 4; ++j) {
            bf16x4 a4 = { (__bf16)pa[j].x, (__bf16)pa[j].y, (__bf16)pa[j].z, (__bf16)pa[j].w };
            bf16x4 b4 = { (__bf16)pb[j].x, (__bf16)pb[j].y, (__bf16)pb[j].z, (__bf16)pb[j].w };
            *(bf16x4*)&As[(sr + 32 * j) * LDT + scol * 4] = a4;
            *(bf16x4*)&Bs[(sr + 32 * j) * LDT + scol * 4] = b4;
        }
        __syncthreads();
        if (kt + 1 < KT) {
            const int koff = (kt + 1) * BK;
#pragma unroll
            for (int j = 0; j < 4; ++j) {
                pa[j] = *(const float4*)(xg + (size_t)j * 32 * D + koff);
                pb[j] = *(const float4*)(yg + (size_t)j * 32 * D + koff);
            }
        }
        bf16x8 af[4], bfr[4];
#pragma unroll
        for (int i = 0; i < 4; ++i) {
            af[i]  = *(const bf16x8*)&As[(wm + i * 16 + ln) * LDT + quad * 8];
            bfr[i] = *(const bf16x8*)&Bs[(wn + i * 16 + ln) * LDT + quad * 8];
        }
#pragma unroll
        for (int mt = 0; mt < 4; ++mt)
#pragma unroll
            for (int nt = 0; nt < 4; ++nt)
                acc[mt][nt] = __builtin_amdgcn_mfma_f32_16x16x32_bf16(
                    af[mt], bfr[nt], acc[mt][nt], 0, 0, 0);
    }

    float yqv[4], syv[4];
    int gcv[4];
#pragma unroll
    for (int nt = 0; nt < 4; ++nt) {
        const int gc = n0 + wn + nt * 16 + ln;
        gcv[nt] = gc;
        yqv[nt] = yq[gc];
        syv[nt] = sy[gc];
    }
#pragma unroll
    for (int mt = 0; mt < 4; ++mt) {
#pragma unroll
        for (int r = 0; r < 4; ++r) {
            const int gm = m0 + wm + mt * 16 + quad * 4 + r;
            const float xqv = xq[gm];
            const float sxv = sx[gm];
            const float omx = 1.0f - xqv;
            float* orow = out + (size_t)gm * V;
#pragma unroll
            for (int nt = 0; nt < 4; ++nt) {
                const float raw = acc[mt][nt][r];
                const float dot = sxv * syv[nt] * raw;
                float d2 = xqv + yqv[nt] - 2.0f * dot;
                float dd = __builtin_amdgcn_sqrtf(fmaxf(d2, 0.0f));
                float denom = omx * (1.0f - yqv[nt]) + EPS;
                float arg = 1.0f + 2.0f * dd * __builtin_amdgcn_rcpf(denom);
                arg = fmaxf(arg, 1.0f + EPS);
                float res = -__logf(arg + __builtin_amdgcn_sqrtf(arg * arg - 1.0f));
                orow[gcv[nt]] = res;
            }
        }
    }
}

// ---------------------------------------------------------------------------
extern "C" void kernel_launch(void* const* d_in, const int* in_sizes, int n_in,
                              void* d_out, int out_size, void* d_ws, size_t ws_size,
                              hipStream_t stream)
{
    const float* X = (const float*)d_in[0];   // hidden_states (N x D) fp32
    const float* Y = (const float*)d_in[1];   // weight        (V x D) fp32
    float* out = (float*)d_out;               // logits (N x V) fp32

    const int N = in_sizes[0] / D;   // 4096
    const int V = in_sizes[1] / D;   // 32000

    // fast path workspace: bf16 X (N*D) + bf16 Y (V*D) + xq (N) + yq (V)
    const size_t need = (size_t)(N + V) * D * 2 + (size_t)(N + V) * 4;

    if (ws_size >= need && (N % 256) == 0 && (V % 256) == 0) {
        __bf16* Xb = (__bf16*)d_ws;
        __bf16* Yb = Xb + (size_t)N * D;
        float* xq = (float*)(Yb + (size_t)V * D);
        float* yq = xq + N;

        project_convert_kernel<<<N, 256, 0, stream>>>(X, Xb, xq);
        project_convert_kernel<<<V, 256, 0, stream>>>(Y, Yb, yq);

        const int nbx = V / 256;               // 125
        const int nwg = nbx * (N / 256);       // 2000
        hyp_gemm_256_kernel<<<nwg, 512, 0, stream>>>(Xb, Yb, xq, yq, out, V, nbx);
    } else {
        float* sx = (float*)d_ws;
        float* xq = sx + N;
        float* sy = xq + N;
        float* yq = sy + V;

        row_stats_kernel<<<N, 256, 0, stream>>>(X, sx, xq);
        row_stats_kernel<<<V, 256, 0, stream>>>(Y, sy, yq);

        dim3 grid(V / FBN, N / FBM);
        hyp_gemm_kernel<<<grid, 256, 0, stream>>>(X, Y, sx, xq, sy, yq, out, V);
    }
}

// Round 4
// 897.540 us; speedup vs baseline: 1.0130x; 1.0021x over previous
//
#include <hip/hip_runtime.h>
#include <math.h>
#include <stdint.h>

#define EPS 1e-5f

typedef __bf16 bf16x8 __attribute__((ext_vector_type(8)));
typedef __bf16 bf16x4 __attribute__((ext_vector_type(4)));
typedef float  f32x4  __attribute__((ext_vector_type(4)));

constexpr int D  = 1024;   // hidden dim (fixed by the reference)

// ---------------------------------------------------------------------------
// Pre-pass: per row compute sum(v*v), projection scale s, write bf16(s*v)
// and q = s^2 * sumsq (projected squared norm). One 256-thread block per row.
// ---------------------------------------------------------------------------
__global__ __launch_bounds__(256) void project_convert_kernel(
    const float* __restrict__ src, __bf16* __restrict__ dst,
    float* __restrict__ q_out)
{
    const int row = blockIdx.x;
    const int t = threadIdx.x;
    const float4 v = *(const float4*)(src + (size_t)row * D + t * 4);
    float s = v.x * v.x + v.y * v.y + v.z * v.z + v.w * v.w;
#pragma unroll
    for (int off = 32; off > 0; off >>= 1) s += __shfl_down(s, off);
    __shared__ float partial[4];
    __shared__ float s_scale;
    if ((t & 63) == 0) partial[t >> 6] = s;
    __syncthreads();
    if (t == 0) {
        float tot = partial[0] + partial[1] + partial[2] + partial[3];
        float norm = sqrtf(tot);
        float sc = fminf((1.0f - EPS) / (norm + 1e-10f), 1.0f);
        s_scale = sc;
        q_out[row] = sc * sc * tot;   // projected ||.||^2, fp32-exact path
    }
    __syncthreads();
    const float sc = s_scale;
    bf16x4 o = { (__bf16)(v.x * sc), (__bf16)(v.y * sc),
                 (__bf16)(v.z * sc), (__bf16)(v.w * sc) };
    *(bf16x4*)(dst + (size_t)row * D + t * 4) = o;
}

// async global->LDS, 16 B per lane. LDS dest = wave-uniform base + lane*16.
__device__ __forceinline__ void gload16(const void* g, void* l)
{
    __builtin_amdgcn_global_load_lds(
        (const __attribute__((address_space(1))) uint32_t*)g,
        (__attribute__((address_space(3))) uint32_t*)l, 16, 0, 0);
}

#define WAITVM(N)  asm volatile("s_waitcnt vmcnt(" #N ")" ::: "memory")
#define WAITLGKM0  asm volatile("s_waitcnt lgkmcnt(0)" ::: "memory")
#define SBAR()     __builtin_amdgcn_s_barrier()
#define SCHED0()   __builtin_amdgcn_sched_barrier(0)

// ---------------------------------------------------------------------------
// 256x256 bf16 GEMM, m201-style 4-phase/K-tile schedule (8 phases / 2 tiles).
// 8 waves (2M x 4N, 128x64 per wave), BK=64 (128 B rows).
// LDS: 8 half-tile slots of 16 KB (A:4, B:4), recycled mod 2 K-tiles.
// Per phase: {ds_read subtile; stage 1 half (2 gload16); barrier; lgkmcnt(0);
// setprio(1); 16 MFMA; setprio(0); barrier}.  vmcnt(6) once per tile boundary
// (3 half-tiles in flight, never drained).  Stage stream skew: ph0(k) stages
// Bhigh(k+1); ph1/2/3(k) stage Blow/Alow/Ahigh(k+2) -- each overwrites a half
// whose last ds_read was drained by an earlier phase's lgkmcnt(0)+barrier.
// Swizzle: granule_phys = granule_log ^ (row&7), via pre-swizzled global src
// (linear LDS dest, rule 21); fragment rows have row&7 == ln&7.
// Fused hyperbolic-distance epilogue.
// ---------------------------------------------------------------------------
__global__ __launch_bounds__(512, 2) void hyp_gemm_256_kernel(
    const __bf16* __restrict__ Xb, const __bf16* __restrict__ Yb,
    const float* __restrict__ xq, const float* __restrict__ yq,
    float* __restrict__ out, int V, int nbx)
{
    constexpr int KT   = D / 64;     // 16 K-tiles of BK=64
    constexpr int HALF = 16384;      // bytes per half-tile slot (128 rows x 128 B)

    __shared__ char As[4 * HALF];    // 64 KB
    __shared__ char Bs[4 * HALF];    // 64 KB

    // n-fastest block order (all XCDs share one M-band -> Y panel L3-shared)
    const int c  = blockIdx.x;
    const int m0 = (c / nbx) * 256;
    const int n0 = (c % nbx) * 256;

    const int t = threadIdx.x;       // 0..511

    // ---- staging map: one gload16 sweep = 512 x 16 B = 64 rows x 128 B.
    // thread t -> row-in-half rt + 64j, granule (t&7) ^ (rt&7) (pre-swizzled).
    const int rt   = t >> 3;                       // 0..63
    const int gsrc = ((t & 7) ^ (rt & 7)) * 16;
    const char* xrow = (const char*)Xb + (size_t)(m0 + rt) * 2048 + gsrc;
    const char* yrow = (const char*)Yb + (size_t)(n0 + rt) * 2048 + gsrc;

    auto STAGE_A = [&](int k, int h) {   // A half h of tile k -> slot (k&1)*2+h
        char* dst = As + ((k & 1) * 2 + h) * HALF + t * 16;
        const char* src = xrow + (size_t)(h * 128) * 2048 + k * 128;
        gload16(src, dst);
        gload16(src + 64 * 2048, dst + 8192);
    };
    auto STAGE_B = [&](int k, int h) {
        char* dst = Bs + ((k & 1) * 2 + h) * HALF + t * 16;
        const char* src = yrow + (size_t)(h * 128) * 2048 + k * 128;
        gload16(src, dst);
        gload16(src + 64 * 2048, dst + 8192);
    };

    // ---- wave/fragment map: 8 waves = 2M x 4N, each 128x64 (8x4 16x16 frags)
    const int lane = t & 63;
    const int ln   = lane & 15;
    const int quad = lane >> 4;
    const int wave = t >> 6;
    const int ha   = wave >> 2;            // my A half (0/1)
    const int hb   = (wave & 3) >> 1;      // my B half (0/1)
    const int brow = (wave & 1) * 64;      // my row base within B half
    const int wm   = ha * 128;             // global row base (epilogue)
    const int wn   = (wave & 3) * 64;      // global col base (epilogue)
    const int swz  = ln & 7;               // row&7 for every fragment row

    // ds_read: A frag (mi,ks): slot + (mi*16+ln)*128 + ((ks*4+quad)^swz)*16
    const int ga0 = ((0 * 4 + quad) ^ swz) * 16;   // ks=0 granule byte
    const int ga1 = ((1 * 4 + quad) ^ swz) * 16;   // ks=1

    f32x4 acc[8][4] = {};
    bf16x8 a03[8], a47[8], b[8];           // [frag*2+ks]

    auto LDA03 = [&](const char* sa) {
#pragma unroll
        for (int i = 0; i < 4; ++i) {
            const char* r = sa + (i * 16 + ln) * 128;
            a03[i * 2 + 0] = *(const bf16x8*)(r + ga0);
            a03[i * 2 + 1] = *(const bf16x8*)(r + ga1);
        }
    };
    auto LDA47 = [&](const char* sa) {
#pragma unroll
        for (int i = 0; i < 4; ++i) {
            const char* r = sa + ((i + 4) * 16 + ln) * 128;
            a47[i * 2 + 0] = *(const bf16x8*)(r + ga0);
            a47[i * 2 + 1] = *(const bf16x8*)(r + ga1);
        }
    };
    auto LDB = [&](const char* sb) {
#pragma unroll
        for (int i = 0; i < 4; ++i) {
            const char* r = sb + (brow + i * 16 + ln) * 128;
            b[i * 2 + 0] = *(const bf16x8*)(r + ga0);
            b[i * 2 + 1] = *(const bf16x8*)(r + ga1);
        }
    };
    auto MM = [&](bf16x8* a, int mBase, int nBase) {   // 4M x 2N x 2ks = 16 MFMA
        __builtin_amdgcn_s_setprio(1);
#pragma unroll
        for (int mi = 0; mi < 4; ++mi)
#pragma unroll
            for (int ni = 0; ni < 2; ++ni)
#pragma unroll
                for (int ks = 0; ks < 2; ++ks)
                    acc[mBase + mi][nBase + ni] =
                        __builtin_amdgcn_mfma_f32_16x16x32_bf16(
                            a[mi * 2 + ks], b[(nBase + ni) * 2 + ks],
                            acc[mBase + mi][nBase + ni], 0, 0, 0);
        __builtin_amdgcn_s_setprio(0);
    };

    // ---- prologue: 7 halves (14 loads). First 4 = all of tile 0.
    STAGE_A(0, 0); STAGE_A(0, 1); STAGE_B(0, 0); STAGE_B(0, 1);
    STAGE_B(1, 0); STAGE_A(1, 0); STAGE_A(1, 1);

#pragma unroll 2
    for (int kt = 0; kt < KT - 2; ++kt) {
        const char* sa = As + ((kt & 1) * 2 + ha) * HALF;
        const char* sb = Bs + ((kt & 1) * 2 + hb) * HALF;
        // tile boundary: everything older than the newest 3 halves has landed
        WAITVM(6); SCHED0(); SBAR(); SCHED0();
        // ph0: read A03 + all B; stage Bhigh(kt+1)
        LDA03(sa); LDB(sb);
        STAGE_B(kt + 1, 1);
        SBAR(); WAITLGKM0; SCHED0();
        MM(a03, 0, 0);                   // A03 x B01
        SBAR();
        // ph1: read A47; stage Blow(kt+2)
        LDA47(sa);
        STAGE_B(kt + 2, 0);
        SBAR(); WAITLGKM0; SCHED0();
        MM(a03, 0, 2);                   // A03 x B23
        SBAR();
        // ph2: stage Alow(kt+2)
        STAGE_A(kt + 2, 0);
        SBAR();
        MM(a47, 4, 2);                   // A47 x B23
        SBAR();
        // ph3: stage Ahigh(kt+2)
        STAGE_A(kt + 2, 1);
        SBAR();
        MM(a47, 4, 0);                   // A47 x B01
        SBAR();
    }
    // ---- tile KT-2 (=14, parity 0): only stage Bhigh(15)
    {
        const char* sa = As + (0 * 2 + ha) * HALF;
        const char* sb = Bs + (0 * 2 + hb) * HALF;
        WAITVM(6); SCHED0(); SBAR(); SCHED0();
        LDA03(sa); LDB(sb);
        STAGE_B(KT - 1, 1);
        SBAR(); WAITLGKM0; SCHED0();
        MM(a03, 0, 0);
        SBAR();
        LDA47(sa);
        SBAR(); WAITLGKM0; SCHED0();
        MM(a03, 0, 2);
        MM(a47, 4, 2);
        MM(a47, 4, 0);
    }
    // ---- tile KT-1 (=15, parity 1): pure compute
    {
        const char* sa = As + (1 * 2 + ha) * HALF;
        const char* sb = Bs + (1 * 2 + hb) * HALF;
        WAITVM(0); SCHED0(); SBAR(); SCHED0();
        LDA03(sa); LDB(sb);
        WAITLGKM0; SCHED0();
        MM(a03, 0, 0);
        MM(a03, 0, 2);
        LDA47(sa);
        WAITLGKM0; SCHED0();
        MM(a47, 4, 2);
        MM(a47, 4, 0);
    }

    // ---------------- epilogue: hyperbolic distance ----------------
    // C/D layout: col = lane&15, row = quad*4 + reg  [m89-verified]
    float yqv[4], omy[4];
    int gcv[4];
#pragma unroll
    for (int nt = 0; nt < 4; ++nt) {
        const int gc = n0 + wn + nt * 16 + ln;
        gcv[nt] = gc;
        yqv[nt] = yq[gc];
        omy[nt] = 1.0f - yqv[nt];
    }
#pragma unroll
    for (int mt = 0; mt < 8; ++mt) {
#pragma unroll
        for (int r = 0; r < 4; ++r) {
            const int gm = m0 + wm + mt * 16 + quad * 4 + r;
            const float xqv = xq[gm];
            const float omx = 1.0f - xqv;
            float* orow = out + (size_t)gm * V;
#pragma unroll
            for (int nt = 0; nt < 4; ++nt) {
                const float dot = acc[mt][nt][r];   // already projected dot
                float d2 = fmaxf(xqv + yqv[nt] - 2.0f * dot, 0.0f);
                float d  = __builtin_amdgcn_sqrtf(d2);
                float denom = omx * omy[nt] + EPS;
                float w = d * __builtin_amdgcn_rcpf(denom);   // = t/2, t = 2d/denom
                float res;
                if (__builtin_expect(w >= 4.0f, 1)) {
                    // arccosh(1+t) ~= log(2+2t), err < 4e-3 for t >= 8
                    res = __logf(2.0f + 4.0f * w);
                } else {
                    float arg = fmaxf(1.0f + 2.0f * w, 1.0f + EPS);
                    res = __logf(arg + __builtin_amdgcn_sqrtf(arg * arg - 1.0f));
                }
                orow[gcv[nt]] = -res;
            }
        }
    }
}

// ---------------------------------------------------------------------------
// FALLBACK PATH (fp32 inputs, 288 KB workspace; verified in round 0)
// ---------------------------------------------------------------------------
constexpr int FBM = 128, FBN = 128;
constexpr int LDT = 40;  // 32 + 8 padded LDS row stride (bf16)

__global__ __launch_bounds__(256) void row_stats_kernel(
    const float* __restrict__ src, float* __restrict__ scale_out,
    float* __restrict__ sq_out)
{
    const int row = blockIdx.x;
    const int t = threadIdx.x;
    const float4 v = *(const float4*)(src + (size_t)row * D + t * 4);
    float s = v.x * v.x + v.y * v.y + v.z * v.z + v.w * v.w;
#pragma unroll
    for (int off = 32; off > 0; off >>= 1) s += __shfl_down(s, off);
    __shared__ float partial[4];
    if ((t & 63) == 0) partial[t >> 6] = s;
    __syncthreads();
    if (t == 0) {
        float tot = partial[0] + partial[1] + partial[2] + partial[3];
        float norm = sqrtf(tot);
        float sc = fminf((1.0f - EPS) / (norm + 1e-10f), 1.0f);
        scale_out[row] = sc;
        sq_out[row] = sc * sc * tot;
    }
}

__global__ __launch_bounds__(256) void hyp_gemm_kernel(
    const float* __restrict__ X, const float* __restrict__ Y,
    const float* __restrict__ sx, const float* __restrict__ xq,
    const float* __restrict__ sy, const float* __restrict__ yq,
    float* __restrict__ out, int V)
{
    constexpr int BK = 32;
    __shared__ __bf16 As[FBM * LDT];
    __shared__ __bf16 Bs[FBN * LDT];

    const int t  = threadIdx.x;
    const int m0 = blockIdx.y * FBM;
    const int n0 = blockIdx.x * FBN;

    const int sr = t >> 3;
    const int scol = t & 7;

    const float* xg = X + (size_t)(m0 + sr) * D + scol * 4;
    const float* yg = Y + (size_t)(n0 + sr) * D + scol * 4;

    const int lane = t & 63;
    const int wave = t >> 6;
    const int wm = (wave & 1) * 64;
    const int wn = (wave >> 1) * 64;
    const int ln = lane & 15;
    const int quad = lane >> 4;

    f32x4 acc[4][4] = {};

    float4 pa[4], pb[4];
#pragma unroll
    for (int j = 0; j < 4; ++j) {
        pa[j] = *(const float4*)(xg + (size_t)j * 32 * D);
        pb[j] = *(const float4*)(yg + (size_t)j * 32 * D);
    }

    constexpr int KT = D / BK;
    for (int kt = 0; kt < KT; ++kt) {
        __syncthreads();
#pragma unroll
        for (int j = 0; j < 4; ++j) {
            bf16x4 a4 = { (__bf16)pa[j].x, (__bf16)pa[j].y, (__bf16)pa[j].z, (__bf16)pa[j].w };
            bf16x4 b4 = { (__bf16)pb[j].x, (__bf16)pb[j].y, (__bf16)pb[j].z, (__bf16)pb[j].w };
            *(bf16x4*)&As[(sr + 32 * j) * LDT + scol * 4] = a4;
            *(bf16x4*)&Bs[(sr + 32 * j) * LDT + scol * 4] = b4;
        }
        __syncthreads();
        if (kt + 1 < KT) {
            const int koff = (kt + 1) * BK;
#pragma unroll
            for (int j = 0; j < 4; ++j) {
                pa[j] = *(const float4*)(xg + (size_t)j * 32 * D + koff);
                pb[j] = *(const float4*)(yg + (size_t)j * 32 * D + koff);
            }
        }
        bf16x8 af[4], bfr[4];
#pragma unroll
        for (int i = 0; i < 4; ++i) {
            af[i]  = *(const bf16x8*)&As[(wm + i * 16 + ln) * LDT + quad * 8];
            bfr[i] = *(const bf16x8*)&Bs[(wn + i * 16 + ln) * LDT + quad * 8];
        }
#pragma unroll
        for (int mt = 0; mt < 4; ++mt)
#pragma unroll
            for (int nt = 0; nt < 4; ++nt)
                acc[mt][nt] = __builtin_amdgcn_mfma_f32_16x16x32_bf16(
                    af[mt], bfr[nt], acc[mt][nt], 0, 0, 0);
    }

    float yqv[4], syv[4];
    int gcv[4];
#pragma unroll
    for (int nt = 0; nt < 4; ++nt) {
        const int gc = n0 + wn + nt * 16 + ln;
        gcv[nt] = gc;
        yqv[nt] = yq[gc];
        syv[nt] = sy[gc];
    }
#pragma unroll
    for (int mt = 0; mt < 4; ++mt) {
#pragma unroll
        for (int r = 0; r < 4; ++r) {
            const int gm = m0 + wm + mt * 16 + quad * 4 + r;
            const float xqv = xq[gm];
            const float sxv = sx[gm];
            const float omx = 1.0f - xqv;
            float* orow = out + (size_t)gm * V;
#pragma unroll
            for (int nt = 0; nt < 4; ++nt) {
                const float raw = acc[mt][nt][r];
                const float dot = sxv * syv[nt] * raw;
                float d2 = xqv + yqv[nt] - 2.0f * dot;
                float dd = __builtin_amdgcn_sqrtf(fmaxf(d2, 0.0f));
                float denom = omx * (1.0f - yqv[nt]) + EPS;
                float arg = 1.0f + 2.0f * dd * __builtin_amdgcn_rcpf(denom);
                arg = fmaxf(arg, 1.0f + EPS);
                float res = -__logf(arg + __builtin_amdgcn_sqrtf(arg * arg - 1.0f));
                orow[gcv[nt]] = res;
            }
        }
    }
}

// ---------------------------------------------------------------------------
extern "C" void kernel_launch(void* const* d_in, const int* in_sizes, int n_in,
                              void* d_out, int out_size, void* d_ws, size_t ws_size,
                              hipStream_t stream)
{
    const float* X = (const float*)d_in[0];   // hidden_states (N x D) fp32
    const float* Y = (const float*)d_in[1];   // weight        (V x D) fp32
    float* out = (float*)d_out;               // logits (N x V) fp32

    const int N = in_sizes[0] / D;   // 4096
    const int V = in_sizes[1] / D;   // 32000

    // fast path workspace: bf16 X (N*D) + bf16 Y (V*D) + xq (N) + yq (V)
    const size_t need = (size_t)(N + V) * D * 2 + (size_t)(N + V) * 4;

    if (ws_size >= need && (N % 256) == 0 && (V % 256) == 0) {
        __bf16* Xb = (__bf16*)d_ws;
        __bf16* Yb = Xb + (size_t)N * D;
        float* xq = (float*)(Yb + (size_t)V * D);
        float* yq = xq + N;

        project_convert_kernel<<<N, 256, 0, stream>>>(X, Xb, xq);
        project_convert_kernel<<<V, 256, 0, stream>>>(Y, Yb, yq);

        const int nbx = V / 256;               // 125
        const int nwg = nbx * (N / 256);       // 2000
        hyp_gemm_256_kernel<<<nwg, 512, 0, stream>>>(Xb, Yb, xq, yq, out, V, nbx);
    } else {
        float* sx = (float*)d_ws;
        float* xq = sx + N;
        float* sy = xq + N;
        float* yq = sy + V;

        row_stats_kernel<<<N, 256, 0, stream>>>(X, sx, xq);
        row_stats_kernel<<<V, 256, 0, stream>>>(Y, sy, yq);

        dim3 grid(V / FBN, N / FBM);
        hyp_gemm_kernel<<<grid, 256, 0, stream>>>(X, Y, sx, xq, sy, yq, out, V);
    }
}